// Round 2
// baseline (123.631 us; speedup 1.0000x reference)
//
#include <hip/hip_runtime.h>
#include <math.h>

#define Bn 8
#define Qn 20
#define Pn 12
#define Nn 4096
#define Gn 2048
#define Mn 1280   /* Q*FACTOR */
#define Fn 64
#define KNB 7     /* K_NEIGHBORS - 1 */
#define SA 8      /* gt splits for chamfer A (2048/256)  */
#define SB 5      /* recon splits for chamfer B (1280/256) */
#define DONE_TARGET 105  /* 104 chamfer reducers + 1 repulsion reducer */

// ---------------- workspace layout (32-bit words) ----------------
// cham  : 0      (1920)   (B,Q,P)
// ns    : 1920   (1920)
// dd    : 3840   (1920)
// cost  : 5760   (1920)
// cnt   : 7680   (96)
// acc   : 7776   (6)      0 cls, 1 param, 2 pvd, 3 rep, 4 ch1, 5 ch2
// done  : 7782   (1)      finale contributor counter
// rep   : 7808   (160)    per-group repulsion partials
// pmA1  : 8192   (81920)  chamfer A partial mins (SA, B*M)
// pmA2  : 90112  (81920)
// pmB1  : 172032 (81920)  (SB, B*G)
// pmB2  : 253952 (81920)  .. 335872
//
// R8 structure: 3-kernel split for latency overlap.
//   K0 cost_kernel  (160): cost matrix + acc zero            (~5us)
//   K1 mid_kernel   (688): hungarian(8) || chamfer(640) || repulsion(40)
//       -> the 41us serial JV chain (VALUBusy 0.2%, 8 CUs) now overlaps the
//          ~35us chamfer partials instead of serializing after them.
//   K2 reduce_kernel(105): chamfer reduce + rep reduce + finalize
// Every producer->consumer crossing is a kernel boundary: no fences/spins
// (R5/R6 showed per-block threadfence costs ~20us in refetches).

__device__ __forceinline__ float aread(float* p) { return atomicAdd(p, 0.0f); }

__device__ __forceinline__ void contribute(float* acc, int* done, float* out) {
    __threadfence();
    int old = atomicAdd(done, 1);
    if (old == DONE_TARGET - 1) {
        __threadfence();
        float a0 = aread(&acc[0]);
        float a1 = aread(&acc[1]);
        float a2 = aread(&acc[2]);
        float a3 = aread(&acc[3]);
        float a4 = aread(&acc[4]);
        float a5 = aread(&acc[5]);
        out[0] = a0 + 0.5f * a1 + 20.f * a2 + a3 + a4 + a5;
    }
}

// --- uniform-index cross-lane helpers (v_readlane: ~8cy vs ds_bpermute ~30cy) ---
__device__ __forceinline__ int rdlane_i(int v, int l) {
    return __builtin_amdgcn_readlane(v, l);
}
__device__ __forceinline__ double rdlane_d(double v, int l) {
    int lo = __builtin_amdgcn_readlane(__double2loint(v), l);
    int hi = __builtin_amdgcn_readlane(__double2hiint(v), l);
    return __hiloint2double(hi, lo);
}
__device__ __forceinline__ unsigned long long shfl_down_u64(unsigned long long x, int off) {
    unsigned int lo = (unsigned int)(x & 0xFFFFFFFFULL);
    unsigned int hi = (unsigned int)(x >> 32);
    lo = __shfl_down(lo, off);
    hi = __shfl_down(hi, off);
    return ((unsigned long long)hi << 32) | lo;
}

// ============ K0: cost matrix (160 blocks, one per (b,q)) ============
__global__ void cost_kernel(const float* __restrict__ pred_normals,
                            const float* __restrict__ pred_distances,
                            const float* __restrict__ gt_normals,
                            const float* __restrict__ gt_distances,
                            const float* __restrict__ points,
                            const int*   __restrict__ gt_masks,
                            float* __restrict__ ws) {
    __shared__ float smem[2 * Pn * 256];
    const int blk = blockIdx.x;
    const int tid = threadIdx.x;

    float* cham = ws;
    float* ns   = ws + 1920;
    float* dd   = ws + 3840;
    float* cost = ws + 5760;
    float* cnt  = ws + 7680;
    float* acc  = ws + 7776;

    if (blk == 0 && tid < 8) acc[tid] = 0.f;   // acc[0..5] + done + pad
    const int b = blk / Qn, q = blk % Qn;
    const float nx = pred_normals[(b * Qn + q) * 3 + 0];
    const float ny = pred_normals[(b * Qn + q) * 3 + 1];
    const float nz = pred_normals[(b * Qn + q) * 3 + 2];
    const float dq = pred_distances[b * Qn + q];

    float accs[Pn], accw[Pn];
#pragma unroll
    for (int p = 0; p < Pn; ++p) { accs[p] = 0.f; accw[p] = 0.f; }

    const float* ptb = points + (size_t)b * Nn * 3;
    const int*   mb  = gt_masks + (size_t)b * Pn * Nn;

    for (int n = tid; n < Nn; n += 256) {
        float px = ptb[n * 3 + 0], py = ptb[n * 3 + 1], pz = ptb[n * 3 + 2];
        float pp = fabsf(px * nx + py * ny + pz * nz - dq);
#pragma unroll
        for (int p = 0; p < Pn; ++p) {
            float m = (float)mb[(size_t)p * Nn + n];
            accs[p] += pp * m;
            accw[p] += m;
        }
    }
#pragma unroll
    for (int p = 0; p < Pn; ++p) {
        smem[p * 256 + tid] = accs[p];
        smem[(p + Pn) * 256 + tid] = accw[p];
    }
    __syncthreads();
    for (int off = 128; off > 0; off >>= 1) {
        if (tid < off) {
#pragma unroll
            for (int r = 0; r < 2 * Pn; ++r) smem[r * 256 + tid] += smem[r * 256 + tid + off];
        }
        __syncthreads();
    }
    if (tid < Pn) {
        const int p = tid;
        float c  = smem[(p + Pn) * 256];
        float cv = smem[p * 256] / fmaxf(c, 1.f);
        float gnx = gt_normals[(b * Pn + p) * 3 + 0];
        float gny = gt_normals[(b * Pn + p) * 3 + 1];
        float gnz = gt_normals[(b * Pn + p) * 3 + 2];
        float nsim = 1.f - fabsf(nx * gnx + ny * gny + nz * gnz);
        float ddv  = fabsf(dq - gt_distances[b * Pn + p]);
        int idx = (b * Qn + q) * Pn + p;
        cham[idx] = cv;
        ns[idx]   = nsim;
        dd[idx]   = ddv;
        cost[idx] = nsim + 0.5f * ddv + 5.f * ((c > 0.f) ? cv : 1.f);
        if (q == 0) cnt[b * Pn + p] = c;
    }
}

// ============ K1: hungarian (8) || chamfer partials (640) || repulsion (40) ============
__global__ void mid_kernel(const float* __restrict__ pred_logits,
                           const float* __restrict__ recon,
                           const float* __restrict__ gt,
                           float* __restrict__ ws) {
    __shared__ float smem[768];
    const int blk = blockIdx.x;
    const int tid = threadIdx.x;

    float* cham = ws;
    float* ns   = ws + 1920;
    float* dd   = ws + 3840;
    float* cost = ws + 5760;
    float* cnt  = ws + 7680;
    float* acc  = ws + 7776;
    float* rep_part = ws + 7808;
    float* pmA1 = ws + 8192;
    float* pmA2 = ws + 90112;
    float* pmB1 = ws + 172032;
    float* pmB2 = ws + 253952;

    if (blk < 8) {
        // ---- wave-parallel transposed rectangular JV + fused cls/param/pvd ----
        // (R7 internals unchanged; reads cost across the K0 kernel boundary.)
        if (tid >= 64) return;
        const int b = blk;
        const int t = tid;
        const int col = t;
        const bool isCol = (col >= 1 && col <= Qn);

        double c[Pn];
#pragma unroll
        for (int k = 0; k < Pn; ++k) c[k] = 0.0;
        if (isCol) {
            const float* cb = cost + ((size_t)b * Qn + (col - 1)) * Pn;
#pragma unroll
            for (int k = 0; k < Pn; ++k) c[k] = (double)cb[k];
        }

        double v = 0.0, u = 0.0, minv = 0.0;
        int way = 0, p = 0;

        for (int i = 1; i <= Pn; ++i) {
            const int p0 = i;
            minv = 1e18;
            bool used = false;
            bool rowInPath = false;
            int j0s = 0;
            while (true) {
                if (col == j0s) used = true;
                int i0s = (j0s == 0) ? p0 : rdlane_i(p, j0s);
                if (t == i0s) rowInPath = true;
                double u_i0 = rdlane_d(u, i0s);
                // register-select row i0s of the cost matrix (i0s is uniform)
                double cij = c[0];
#pragma unroll
                for (int k = 1; k < Pn; ++k) cij = (i0s == k + 1) ? c[k] : cij;
                if (isCol && !used) {
                    double cur = cij - u_i0 - v;
                    if (cur < minv) { minv = cur; way = j0s; }
                }
                double mv = (isCol && !used) ? minv : 1e18;
                // pack (mv, col) into monotone u64 key; min-reduce over lanes 0..31
                long long sbits = __double_as_longlong(mv);
                unsigned long long key = (unsigned long long)sbits;
                key = (sbits < 0) ? ~key : (key | 0x8000000000000000ULL);
                key = (key & ~63ULL) | (unsigned long long)(unsigned)col;
#pragma unroll
                for (int off = 16; off > 0; off >>= 1) {
                    unsigned long long o = shfl_down_u64(key, off);
                    key = (o < key) ? o : key;
                }
                int klo = rdlane_i((int)(unsigned)(key & 0xFFFFFFFFULL), 0);
                int khi = rdlane_i((int)(unsigned)(key >> 32), 0);
                unsigned long long kmin =
                    ((unsigned long long)(unsigned)khi << 32) | (unsigned)klo;
                int j1 = (int)(kmin & 63ULL);
                unsigned long long ub = kmin & ~63ULL;
                long long sres = (ub >> 63) ? (long long)(ub ^ 0x8000000000000000ULL)
                                            : ~(long long)ub;
                double delta = __longlong_as_double(sres);
                if (used || col == 0) v -= delta;
                else if (isCol)       minv -= delta;
                if (rowInPath)        u += delta;
                j0s = j1;
                int pj0 = rdlane_i(p, j0s);
                if (pj0 == 0) break;
            }
            while (j0s != 0) {
                int wj = rdlane_i(way, j0s);
                int pw = (wj == 0) ? p0 : rdlane_i(p, wj);
                if (col == j0s) p = pw;
                j0s = wj;
            }
        }

        float cls = 0.f, par = 0.f, pvd = 0.f;
        if (isCol) {
            float x = pred_logits[b * Qn + (col - 1)];
            float tgt = (p > 0) ? 1.f : 0.f;
            cls = fmaxf(x, 0.f) - x * tgt + log1pf(expf(-fabsf(x)));
            if (p > 0) {
                int idx = (b * Qn + (col - 1)) * Pn + (p - 1);
                par = ns[idx] + dd[idx];
                pvd = (cnt[b * Pn + (p - 1)] > 0.f) ? cham[idx] : 0.f;
            }
        }
        for (int off = 32; off > 0; off >>= 1) {
            cls += __shfl_down(cls, off);
            par += __shfl_down(par, off);
            pvd += __shfl_down(pvd, off);
        }
        if (t == 0) {
            atomicAdd(&acc[0], cls / (float)(Bn * Qn));
            atomicAdd(&acc[1], par / (float)(Bn * Pn));
            atomicAdd(&acc[2], pvd / (float)(Bn * Pn));
        }
        return;
    } else if (blk < 648) {
        // ---- chamfer partial: LDS-tiled 256-pt inner chunk (R3-proven) ----
        int cblk = blk - 8;
        float* tx = smem;
        float* ty = smem + 256;
        float* tz = smem + 512;
        float x, y, z;
        const float* inner;
        float *o1, *o2;
        int idx;
        if (cblk < 40 * SA) {
            int s = cblk % SA, ob = cblk / SA;
            idx = ob * 256 + tid;                 // over B*M
            int b = idx / Mn;
            x = recon[idx * 3 + 0]; y = recon[idx * 3 + 1]; z = recon[idx * 3 + 2];
            inner = gt + ((size_t)b * Gn + s * 256) * 3;
            o1 = pmA1 + s * (Bn * Mn); o2 = pmA2 + s * (Bn * Mn);
        } else {
            cblk -= 40 * SA;
            int s = cblk % SB, ob = cblk / SB;
            idx = ob * 256 + tid;                 // over B*G
            int b = idx / Gn;
            x = gt[idx * 3 + 0]; y = gt[idx * 3 + 1]; z = gt[idx * 3 + 2];
            inner = recon + ((size_t)b * Mn + s * 256) * 3;
            o1 = pmB1 + s * (Bn * Gn); o2 = pmB2 + s * (Bn * Gn);
        }
        tx[tid] = inner[tid * 3 + 0];
        ty[tid] = inner[tid * 3 + 1];
        tz[tid] = inner[tid * 3 + 2];
        __syncthreads();
        float m1 = 3.4e38f, m2 = 3.4e38f;
        for (int j = 0; j < 256; ++j) {
            float dx = x - tx[j], dy = y - ty[j], dz = z - tz[j];
            float d1 = fabsf(dx) + fabsf(dy) + fabsf(dz);
            float d2 = dx * dx + dy * dy + dz * dz;
            m1 = fminf(m1, d1); m2 = fminf(m2, d2);
        }
        o1[idx] = m1; o2[idx] = m2;
    } else {
        // ---- repulsion: 4 waves per block, one (b,q) 64-pt group per wave ----
        // Branchless kNN ladder (compile-time indices only, R7-proven).
        const int wave = tid >> 6, lane = tid & 63;
        const int g = (blk - 648) * 4 + wave;
        float* xs = smem + wave * 192;
        float* ys = xs + 64;
        float* zs = xs + 128;
        const float* base = recon + (size_t)g * Fn * 3;
        xs[lane] = base[lane * 3 + 0];
        ys[lane] = base[lane * 3 + 1];
        zs[lane] = base[lane * 3 + 2];
        // wave-local LDS region: wave-synchronous access
        float best[KNB];
#pragma unroll
        for (int k = 0; k < KNB; ++k) best[k] = 3.4e38f;
        const float xi = xs[lane], yi = ys[lane], zi = zs[lane];
        for (int j = 0; j < Fn; ++j) {
            float dx = xi - xs[j], dy = yi - ys[j], dz = zi - zs[j];
            float d2 = dx * dx + dy * dy + dz * dz;
            d2 = (j == lane) ? 3.4e38f : d2;   // exclude self, keep lanes convergent
#pragma unroll
            for (int k = 0; k < KNB; ++k) {    // one bubble pass; best stays sorted asc
                float lo = fminf(best[k], d2);
                float hi = fmaxf(best[k], d2);
                best[k] = lo;
                d2 = hi;
            }
        }
        float sum = 0.f;
#pragma unroll
        for (int k = 0; k < KNB; ++k) {
            float dn = fmaxf(best[k], 1e-12f);
            float w  = expf(-dn / (0.03f * 0.03f));
            sum += (0.07f - sqrtf(dn)) * w;
        }
        for (int off = 32; off > 0; off >>= 1) sum += __shfl_down(sum, off);
        if (lane == 0) rep_part[g] = fmaxf(sum / (float)(Fn * KNB), 0.f);
    }
}

// ============ K2: chamfer reduce (104) + repulsion reduce (1) + finalize ============
__global__ void reduce_kernel(float* __restrict__ ws, float* __restrict__ out) {
    const int blk = blockIdx.x;
    const int tid = threadIdx.x;

    float* acc  = ws + 7776;
    int*   done = (int*)(ws + 7782);
    float* rep_part = ws + 7808;
    float* pmA1 = ws + 8192;
    float* pmA2 = ws + 90112;
    float* pmB1 = ws + 172032;
    float* pmB2 = ws + 253952;

    __shared__ float s1[256], s2[256];
    const int cblk = blk;
    float c1 = 0.f, c2 = 0.f;
    if (cblk < 40) {
        int idx = cblk * 256 + tid;
        float m1 = 3.4e38f, m2 = 3.4e38f;
#pragma unroll
        for (int s = 0; s < SA; ++s) {
            m1 = fminf(m1, pmA1[s * (Bn * Mn) + idx]);
            m2 = fminf(m2, pmA2[s * (Bn * Mn) + idx]);
        }
        c1 = m1 * (0.5f / (float)(Bn * Mn));
        c2 = m2 * (0.5f / (float)(Bn * Mn));
    } else if (cblk < 104) {
        int idx = (cblk - 40) * 256 + tid;
        float m1 = 3.4e38f, m2 = 3.4e38f;
#pragma unroll
        for (int s = 0; s < SB; ++s) {
            m1 = fminf(m1, pmB1[s * (Bn * Gn) + idx]);
            m2 = fminf(m2, pmB2[s * (Bn * Gn) + idx]);
        }
        c1 = m1 * (0.5f / (float)(Bn * Gn));
        c2 = m2 * (0.5f / (float)(Bn * Gn));
    } else {
        c1 = (tid < Bn * Qn) ? rep_part[tid] / (float)(Bn * Qn) : 0.f;
    }
    s1[tid] = c1; s2[tid] = c2;
    __syncthreads();
    for (int off = 128; off > 0; off >>= 1) {
        if (tid < off) { s1[tid] += s1[tid + off]; s2[tid] += s2[tid + off]; }
        __syncthreads();
    }
    if (tid == 0) {
        if (cblk < 104) {
            atomicAdd(&acc[4], s1[0]);
            atomicAdd(&acc[5], s2[0]);
        } else {
            atomicAdd(&acc[3], s1[0]);
        }
        contribute(acc, done, out);
    }
}

extern "C" void kernel_launch(void* const* d_in, const int* in_sizes, int n_in,
                              void* d_out, int out_size, void* d_ws, size_t ws_size,
                              hipStream_t stream) {
    const float* pred_logits    = (const float*)d_in[0];
    const float* pred_normals   = (const float*)d_in[1];
    const float* pred_distances = (const float*)d_in[2];
    const float* gt_normals     = (const float*)d_in[3];
    const float* gt_distances   = (const float*)d_in[4];
    const int*   gt_masks       = (const int*)d_in[5];
    const float* points         = (const float*)d_in[6];
    const float* recon          = (const float*)d_in[7];
    const float* gt             = (const float*)d_in[8];
    // d_in[9] (gt_index) is unused by the reference.

    cost_kernel<<<160, 256, 0, stream>>>(pred_normals, pred_distances, gt_normals,
                                         gt_distances, points, gt_masks, (float*)d_ws);
    mid_kernel<<<688, 256, 0, stream>>>(pred_logits, recon, gt, (float*)d_ws);
    reduce_kernel<<<105, 256, 0, stream>>>((float*)d_ws, (float*)d_out);
}

// Round 3
// 108.998 us; speedup vs baseline: 1.1343x; 1.1343x over previous
//
#include <hip/hip_runtime.h>
#include <math.h>

#define Bn 8
#define Qn 20
#define Pn 12
#define Nn 4096
#define Gn 2048
#define Mn 1280   /* Q*FACTOR */
#define Fn 64
#define KNB 7     /* K_NEIGHBORS - 1 */
#define SA 8      /* gt splits for chamfer A (2048/256)  */
#define SB 5      /* recon splits for chamfer B (1280/256) */
#define DONE_TARGET 113  /* 8 hungarian + 104 chamfer reducers + 1 repulsion reducer */

// ---------------- workspace layout (32-bit words) ----------------
// cham  : 0      (1920)   (B,Q,P)
// ns    : 1920   (1920)
// dd    : 3840   (1920)
// cost  : 5760   (1920)
// cnt   : 7680   (96)
// acc   : 7776   (6)      0 cls, 1 param, 2 pvd, 3 rep, 4 ch1, 5 ch2
// done  : 7782   (1)      finale contributor counter
// rep   : 7808   (160)    per-group repulsion partials
// pmA1  : 8192   (81920)  chamfer A partial mins (SA, B*M)
// pmA2  : 90112  (81920)
// pmB1  : 172032 (81920)  (SB, B*G)
// pmB2  : 253952 (81920)  .. 335872
//
// R9: revert to R7 2-kernel structure (R8 3-way split was neutral: overlap
// premise wrong; accounting for R7 balanced exactly at 41 fill + 39 mega1 +
// 41 finale). Attack the JV chain directly instead:
//  - f32 JV (any exact solver returns the SAME unique optimal assignment;
//    f32 error ~1e-6 << inter-assignment gaps) -> 1 readlane per fetch.
//  - DPP v_min_u32 wave reduce (row_shr 1/2/4/8 + bcast15/31, ~40cy) replaces
//    the 10-dependent-ds_bpermute u64 shuffle reduce (~500cy). Key = monotone
//    f32 bits with col in low 5 bits; tie-break lowest col == reference's
//    ascending strict-< scan. delta fetched EXACT via readlane from argmin lane.
//  - depth-4 cndmask tree for the uniform-row cost select (was 11-deep chain).
//  - mega1 chamfer: float4 LDS tile (ds_read_b128 broadcast) + unroll 4.

__device__ __forceinline__ float aread(float* p) { return atomicAdd(p, 0.0f); }

__device__ __forceinline__ void contribute(float* acc, int* done, float* out) {
    __threadfence();
    int old = atomicAdd(done, 1);
    if (old == DONE_TARGET - 1) {
        __threadfence();
        float a0 = aread(&acc[0]);
        float a1 = aread(&acc[1]);
        float a2 = aread(&acc[2]);
        float a3 = aread(&acc[3]);
        float a4 = aread(&acc[4]);
        float a5 = aread(&acc[5]);
        out[0] = a0 + 0.5f * a1 + 20.f * a2 + a3 + a4 + a5;
    }
}

// --- cross-lane helpers ---
__device__ __forceinline__ int rdlane_i(int v, int l) {
    return __builtin_amdgcn_readlane(v, l);
}
__device__ __forceinline__ float rdlane_f(float v, int l) {
    return __int_as_float(__builtin_amdgcn_readlane(__float_as_int(v), l));
}
// full-wave min via DPP (VALU pipe, ~6 dependent ops); result valid in lane 63.
__device__ __forceinline__ unsigned wave_min_u32(unsigned x) {
    unsigned t;
    t = (unsigned)__builtin_amdgcn_update_dpp((int)0xFFFFFFFF, (int)x, 0x111, 0xF, 0xF, false);
    x = t < x ? t : x;   // row_shr:1
    t = (unsigned)__builtin_amdgcn_update_dpp((int)0xFFFFFFFF, (int)x, 0x112, 0xF, 0xF, false);
    x = t < x ? t : x;   // row_shr:2
    t = (unsigned)__builtin_amdgcn_update_dpp((int)0xFFFFFFFF, (int)x, 0x114, 0xF, 0xF, false);
    x = t < x ? t : x;   // row_shr:4
    t = (unsigned)__builtin_amdgcn_update_dpp((int)0xFFFFFFFF, (int)x, 0x118, 0xF, 0xF, false);
    x = t < x ? t : x;   // row_shr:8  -> lane 15/31/47/63 hold row mins
    t = (unsigned)__builtin_amdgcn_update_dpp((int)0xFFFFFFFF, (int)x, 0x142, 0xF, 0xF, false);
    x = t < x ? t : x;   // row_bcast:15 -> lane 31 = min(0..31), 63 = min(32..63)
    t = (unsigned)__builtin_amdgcn_update_dpp((int)0xFFFFFFFF, (int)x, 0x143, 0xF, 0xF, false);
    x = t < x ? t : x;   // row_bcast:31 -> lane 63 = min(all)
    return x;
}

// ============ K1: cost (160) + repulsion (40) + chamfer partials (640) ============
// Plain stores only; no fences; block 0 zeroes acc+done (visible at kernel boundary).
__global__ void mega1_kernel(const float* __restrict__ pred_normals,
                             const float* __restrict__ pred_distances,
                             const float* __restrict__ gt_normals,
                             const float* __restrict__ gt_distances,
                             const float* __restrict__ points,
                             const int*   __restrict__ gt_masks,
                             const float* __restrict__ recon,
                             const float* __restrict__ gt,
                             float* __restrict__ ws) {
    __shared__ __align__(16) float smem[2 * Pn * 256];
    const int blk = blockIdx.x;
    const int tid = threadIdx.x;

    float* cham = ws;
    float* ns   = ws + 1920;
    float* dd   = ws + 3840;
    float* cost = ws + 5760;
    float* cnt  = ws + 7680;
    float* acc  = ws + 7776;            // words 7776..7783 incl. done @7782
    float* rep_part = ws + 7808;
    float* pmA1 = ws + 8192;
    float* pmA2 = ws + 90112;
    float* pmB1 = ws + 172032;
    float* pmB2 = ws + 253952;

    if (blk < 160) {
        // ---- cost path: one block per (b,q) ----
        if (blk == 0 && tid < 8) acc[tid] = 0.f;   // acc[0..5] + done + pad
        const int b = blk / Qn, q = blk % Qn;
        const float nx = pred_normals[(b * Qn + q) * 3 + 0];
        const float ny = pred_normals[(b * Qn + q) * 3 + 1];
        const float nz = pred_normals[(b * Qn + q) * 3 + 2];
        const float dq = pred_distances[b * Qn + q];

        float accs[Pn], accw[Pn];
#pragma unroll
        for (int p = 0; p < Pn; ++p) { accs[p] = 0.f; accw[p] = 0.f; }

        const float* ptb = points + (size_t)b * Nn * 3;
        const int*   mb  = gt_masks + (size_t)b * Pn * Nn;

        for (int n = tid; n < Nn; n += 256) {
            float px = ptb[n * 3 + 0], py = ptb[n * 3 + 1], pz = ptb[n * 3 + 2];
            float pp = fabsf(px * nx + py * ny + pz * nz - dq);
#pragma unroll
            for (int p = 0; p < Pn; ++p) {
                float m = (float)mb[(size_t)p * Nn + n];
                accs[p] += pp * m;
                accw[p] += m;
            }
        }
#pragma unroll
        for (int p = 0; p < Pn; ++p) {
            smem[p * 256 + tid] = accs[p];
            smem[(p + Pn) * 256 + tid] = accw[p];
        }
        __syncthreads();
        for (int off = 128; off > 0; off >>= 1) {
            if (tid < off) {
#pragma unroll
                for (int r = 0; r < 2 * Pn; ++r) smem[r * 256 + tid] += smem[r * 256 + tid + off];
            }
            __syncthreads();
        }
        if (tid < Pn) {
            const int p = tid;
            float c  = smem[(p + Pn) * 256];
            float cv = smem[p * 256] / fmaxf(c, 1.f);
            float gnx = gt_normals[(b * Pn + p) * 3 + 0];
            float gny = gt_normals[(b * Pn + p) * 3 + 1];
            float gnz = gt_normals[(b * Pn + p) * 3 + 2];
            float nsim = 1.f - fabsf(nx * gnx + ny * gny + nz * gnz);
            float ddv  = fabsf(dq - gt_distances[b * Pn + p]);
            int idx = (b * Qn + q) * Pn + p;
            cham[idx] = cv;
            ns[idx]   = nsim;
            dd[idx]   = ddv;
            cost[idx] = nsim + 0.5f * ddv + 5.f * ((c > 0.f) ? cv : 1.f);
            if (q == 0) cnt[b * Pn + p] = c;
        }
    } else if (blk < 200) {
        // ---- repulsion: 4 waves per block, one (b,q) 64-pt group per wave ----
        // Branchless kNN ladder (compile-time indices only, R7-proven).
        const int wave = tid >> 6, lane = tid & 63;
        const int g = (blk - 160) * 4 + wave;
        float* xs = smem + wave * 192;
        float* ys = xs + 64;
        float* zs = xs + 128;
        const float* base = recon + (size_t)g * Fn * 3;
        xs[lane] = base[lane * 3 + 0];
        ys[lane] = base[lane * 3 + 1];
        zs[lane] = base[lane * 3 + 2];
        // wave-local LDS region: wave-synchronous access
        float best[KNB];
#pragma unroll
        for (int k = 0; k < KNB; ++k) best[k] = 3.4e38f;
        const float xi = xs[lane], yi = ys[lane], zi = zs[lane];
        for (int j = 0; j < Fn; ++j) {
            float dx = xi - xs[j], dy = yi - ys[j], dz = zi - zs[j];
            float d2 = dx * dx + dy * dy + dz * dz;
            d2 = (j == lane) ? 3.4e38f : d2;   // exclude self, keep lanes convergent
#pragma unroll
            for (int k = 0; k < KNB; ++k) {    // one bubble pass; best stays sorted asc
                float lo = fminf(best[k], d2);
                float hi = fmaxf(best[k], d2);
                best[k] = lo;
                d2 = hi;
            }
        }
        float sum = 0.f;
#pragma unroll
        for (int k = 0; k < KNB; ++k) {
            float dn = fmaxf(best[k], 1e-12f);
            float w  = expf(-dn / (0.03f * 0.03f));
            sum += (0.07f - sqrtf(dn)) * w;
        }
        for (int off = 32; off > 0; off >>= 1) sum += __shfl_down(sum, off);
        if (lane == 0) rep_part[g] = fmaxf(sum / (float)(Fn * KNB), 0.f);
    } else {
        // ---- chamfer partial: float4 LDS tile (b128 broadcast reads) + unroll 4 ----
        int cblk = blk - 200;
        float4* tile = reinterpret_cast<float4*>(smem);
        float x, y, z;
        const float* inner;
        float *o1, *o2;
        int idx;
        if (cblk < 40 * SA) {
            int s = cblk % SA, ob = cblk / SA;
            idx = ob * 256 + tid;                 // over B*M
            int b = idx / Mn;
            x = recon[idx * 3 + 0]; y = recon[idx * 3 + 1]; z = recon[idx * 3 + 2];
            inner = gt + ((size_t)b * Gn + s * 256) * 3;
            o1 = pmA1 + s * (Bn * Mn); o2 = pmA2 + s * (Bn * Mn);
        } else {
            cblk -= 40 * SA;
            int s = cblk % SB, ob = cblk / SB;
            idx = ob * 256 + tid;                 // over B*G
            int b = idx / Gn;
            x = gt[idx * 3 + 0]; y = gt[idx * 3 + 1]; z = gt[idx * 3 + 2];
            inner = recon + ((size_t)b * Mn + s * 256) * 3;
            o1 = pmB1 + s * (Bn * Gn); o2 = pmB2 + s * (Bn * Gn);
        }
        {
            const float* ip = inner + tid * 3;
            float4 tv;
            tv.x = ip[0]; tv.y = ip[1]; tv.z = ip[2]; tv.w = 0.f;
            tile[tid] = tv;
        }
        __syncthreads();
        float m1 = 3.4e38f, m2 = 3.4e38f;
#pragma unroll 4
        for (int j = 0; j < 256; ++j) {
            float4 tv = tile[j];
            float dx = x - tv.x, dy = y - tv.y, dz = z - tv.z;
            float d1 = fabsf(dx) + fabsf(dy) + fabsf(dz);
            float d2 = dx * dx + dy * dy + dz * dz;
            m1 = fminf(m1, d1); m2 = fminf(m2, d2);
        }
        o1[idx] = m1; o2[idx] = m2;
    }
}

// ============ K2 finale: hungarian (8) + chamfer reduce (104) + rep reduce (1) ============
__global__ void finale_kernel(const float* __restrict__ pred_logits,
                              float* __restrict__ ws, float* __restrict__ out) {
    const int blk = blockIdx.x;
    const int tid = threadIdx.x;

    float* cham = ws;
    float* ns   = ws + 1920;
    float* dd   = ws + 3840;
    float* cost = ws + 5760;
    float* cnt  = ws + 7680;
    float* acc  = ws + 7776;
    int*   done = (int*)(ws + 7782);
    float* rep_part = ws + 7808;
    float* pmA1 = ws + 8192;
    float* pmA2 = ws + 90112;
    float* pmB1 = ws + 172032;
    float* pmB2 = ws + 253952;

    if (blk < 8) {
        // ---- wave-parallel transposed rectangular JV, f32 + DPP argmin ----
        // Exactness: the optimal assignment is unique a.s.; f32 JV (err ~1e-6,
        // gaps ~1e-2) returns the same matching, hence a bitwise-identical loss.
        if (tid >= 64) return;
        const int b = blk;
        const int t = tid;
        const int col = t;
        const bool isCol = (col >= 1 && col <= Qn);

        float cr[Pn];
#pragma unroll
        for (int k = 0; k < Pn; ++k) cr[k] = 0.f;
        if (isCol) {
            const float* cb = cost + ((size_t)b * Qn + (col - 1)) * Pn;
#pragma unroll
            for (int k = 0; k < Pn; ++k) cr[k] = cb[k];
        }

        float v = 0.f, u = 0.f, minv = 0.f;
        int way = 0, p = 0;

        for (int i = 1; i <= Pn; ++i) {
            minv = 1e30f;
            bool used = false;
            bool rowInPath = false;
            int j0s = 0;
            while (true) {
                if (col == j0s) used = true;
                int i0s = (j0s == 0) ? i : rdlane_i(p, j0s);
                if (t == i0s) rowInPath = true;
                float u_i0 = rdlane_f(u, i0s);
                // depth-4 select of cr[i0s-1] (i0s wave-uniform, 1..12)
                const int bs = i0s - 1;
                float l10 = (bs & 1) ? cr[1]  : cr[0];
                float l11 = (bs & 1) ? cr[3]  : cr[2];
                float l12 = (bs & 1) ? cr[5]  : cr[4];
                float l13 = (bs & 1) ? cr[7]  : cr[6];
                float l14 = (bs & 1) ? cr[9]  : cr[8];
                float l15 = (bs & 1) ? cr[11] : cr[10];
                float l20 = (bs & 2) ? l11 : l10;
                float l21 = (bs & 2) ? l13 : l12;
                float l22 = (bs & 2) ? l15 : l14;
                float cij = (bs >= 8) ? l22 : ((bs >= 4) ? l21 : l20);
                if (isCol && !used) {
                    float cur = cij - u_i0 - v;
                    if (cur < minv) { minv = cur; way = j0s; }
                }
                float mv = (isCol && !used) ? minv : 1e30f;
                // monotone u32 key, col in low 5 bits (col<=20<32); min => lowest
                // col on equal key == reference's ascending strict-< scan.
                unsigned kb = __float_as_uint(mv);
                kb = ((int)kb < 0) ? ~kb : (kb | 0x80000000u);
                kb = (kb & ~31u) | (unsigned)(col & 31);
                unsigned kmin = (unsigned)rdlane_i((int)wave_min_u32(kb), 63);
                int j1 = (int)(kmin & 31u);
                float delta = rdlane_f(minv, j1);   // exact lane value, not key bits
                if (used || col == 0) v -= delta;
                else if (isCol)       minv -= delta;
                if (rowInPath)        u += delta;
                j0s = j1;
                int pj0 = rdlane_i(p, j0s);
                if (pj0 == 0) break;
            }
            while (j0s != 0) {
                int wj = rdlane_i(way, j0s);
                int pw = (wj == 0) ? i : rdlane_i(p, wj);
                if (col == j0s) p = pw;
                j0s = wj;
            }
        }

        float cls = 0.f, par = 0.f, pvd = 0.f;
        if (isCol) {
            float x = pred_logits[b * Qn + (col - 1)];
            float tgt = (p > 0) ? 1.f : 0.f;
            cls = fmaxf(x, 0.f) - x * tgt + log1pf(expf(-fabsf(x)));
            if (p > 0) {
                int idx = (b * Qn + (col - 1)) * Pn + (p - 1);
                par = ns[idx] + dd[idx];
                pvd = (cnt[b * Pn + (p - 1)] > 0.f) ? cham[idx] : 0.f;
            }
        }
        for (int off = 32; off > 0; off >>= 1) {
            cls += __shfl_down(cls, off);
            par += __shfl_down(par, off);
            pvd += __shfl_down(pvd, off);
        }
        if (t == 0) {
            atomicAdd(&acc[0], cls / (float)(Bn * Qn));
            atomicAdd(&acc[1], par / (float)(Bn * Pn));
            atomicAdd(&acc[2], pvd / (float)(Bn * Pn));
            contribute(acc, done, out);
        }
        return;
    }

    // ---- chamfer reduce (blocks 8..111) + repulsion reduce (block 112) ----
    __shared__ float s1[256], s2[256];
    const int cblk = blk - 8;
    float c1 = 0.f, c2 = 0.f;
    if (cblk < 40) {
        int idx = cblk * 256 + tid;
        float m1 = 3.4e38f, m2 = 3.4e38f;
#pragma unroll
        for (int s = 0; s < SA; ++s) {
            m1 = fminf(m1, pmA1[s * (Bn * Mn) + idx]);
            m2 = fminf(m2, pmA2[s * (Bn * Mn) + idx]);
        }
        c1 = m1 * (0.5f / (float)(Bn * Mn));
        c2 = m2 * (0.5f / (float)(Bn * Mn));
    } else if (cblk < 104) {
        int idx = (cblk - 40) * 256 + tid;
        float m1 = 3.4e38f, m2 = 3.4e38f;
#pragma unroll
        for (int s = 0; s < SB; ++s) {
            m1 = fminf(m1, pmB1[s * (Bn * Gn) + idx]);
            m2 = fminf(m2, pmB2[s * (Bn * Gn) + idx]);
        }
        c1 = m1 * (0.5f / (float)(Bn * Gn));
        c2 = m2 * (0.5f / (float)(Bn * Gn));
    } else {
        c1 = (tid < Bn * Qn) ? rep_part[tid] / (float)(Bn * Qn) : 0.f;
    }
    s1[tid] = c1; s2[tid] = c2;
    __syncthreads();
    for (int off = 128; off > 0; off >>= 1) {
        if (tid < off) { s1[tid] += s1[tid + off]; s2[tid] += s2[tid + off]; }
        __syncthreads();
    }
    if (tid == 0) {
        if (cblk < 104) {
            atomicAdd(&acc[4], s1[0]);
            atomicAdd(&acc[5], s2[0]);
        } else {
            atomicAdd(&acc[3], s1[0]);
        }
        contribute(acc, done, out);
    }
}

extern "C" void kernel_launch(void* const* d_in, const int* in_sizes, int n_in,
                              void* d_out, int out_size, void* d_ws, size_t ws_size,
                              hipStream_t stream) {
    const float* pred_logits    = (const float*)d_in[0];
    const float* pred_normals   = (const float*)d_in[1];
    const float* pred_distances = (const float*)d_in[2];
    const float* gt_normals     = (const float*)d_in[3];
    const float* gt_distances   = (const float*)d_in[4];
    const int*   gt_masks       = (const int*)d_in[5];
    const float* points         = (const float*)d_in[6];
    const float* recon          = (const float*)d_in[7];
    const float* gt             = (const float*)d_in[8];
    // d_in[9] (gt_index) is unused by the reference.

    mega1_kernel<<<840, 256, 0, stream>>>(pred_normals, pred_distances, gt_normals,
                                          gt_distances, points, gt_masks, recon, gt,
                                          (float*)d_ws);
    finale_kernel<<<113, 256, 0, stream>>>(pred_logits, (float*)d_ws, (float*)d_out);
}